// Round 4
// baseline (280.999 us; speedup 1.0000x reference)
//
#include <hip/hip_runtime.h>
#include <math.h>

// NUFFT roundtrip on bf16 MFMA (16x16x32), fp32 accumulate.
// fwd:  D[y][m] = sum_x imgT[y][x] * Ax[m][x];  ksp[m] = sum_y D[y][m]*Ay[m][y] (fused epi)
// adj:  out[x][y] = sum_m conjAx[x][m] * U[m][y],  U = ksp * conjAy  (precomputed by gen_U
//       when ws_size permits; else scaled in-staging as fallback), split-K over m.

#define NN      320
#define BCC     8
#define MREAL   6008
#define MSTR    6144          // padded m stride, 96*64
#define MT1     47            // fwd m-tiles of 128 -> 6016 cols
#define P1STR   6016
#define SKADJ   4
#define CHUNKM  (MSTR / SKADJ)   // 1536
#define TWOPI   6.283185307179586f

typedef __attribute__((ext_vector_type(8))) short short8_t;
typedef __attribute__((ext_vector_type(4))) float float4_t;

__device__ __forceinline__ unsigned short f2bf(float f) {
    union { float f; unsigned u; } v; v.f = f;
    unsigned r = v.u + 0x7fff + ((v.u >> 16) & 1);
    return (unsigned short)(r >> 16);
}
__device__ __forceinline__ float bf2f(unsigned short h) {
    union { unsigned u; float f; } v; v.u = ((unsigned)h) << 16;
    return v.f;
}
__device__ __forceinline__ short8_t neg8(short8_t v) {
    short8_t r;
    #pragma unroll
    for (int i = 0; i < 8; ++i) r[i] = v[i] ^ (short)0x8000;
    return r;
}
__device__ __forceinline__ float gval(int i) { return (float)(i - NN/2); }

__device__ __forceinline__ void phase_cs(float k, float g, float* c, float* s) {
    float rev = k * (g * (1.0f / (float)NN));
    rev -= rintf(rev);
    float th = rev * TWOPI;
    __sincosf(th, s, c);
}

// ============ gen_A: build Ax[m][x], AxTc[x][m], AyT[y][m] ============
__global__ __launch_bounds__(256) void gen_A(
    const float* __restrict__ traj,
    unsigned short* __restrict__ Ax_r, unsigned short* __restrict__ Ax_i,
    unsigned short* __restrict__ AxT_r, unsigned short* __restrict__ AxT_i,
    unsigned short* __restrict__ AyT_r, unsigned short* __restrict__ AyT_i)
{
    __shared__ __align__(16) float lc[64][65];
    __shared__ __align__(16) float ls[64][65];
    __shared__ float kxv[64], kyv[64];
    const int tid = threadIdx.x;
    const int m0 = blockIdx.x * 64;
    const int g0 = blockIdx.y * 64;

    if (tid < 64) {
        int m = m0 + tid;
        kxv[tid] = (m < MREAL) ? traj[2*m]     : 0.f;
        kyv[tid] = (m < MREAL) ? traj[2*m + 1] : 0.f;
    }
    __syncthreads();

    #pragma unroll
    for (int it = 0; it < 16; ++it) {
        int e = tid + it * 256;
        int mi = e >> 6, gi = e & 63;
        float c, s;
        phase_cs(kxv[mi], gval(g0 + gi), &c, &s);
        bool valid = (m0 + mi) < MREAL;
        lc[mi][gi] = valid ? c : 0.f;
        ls[mi][gi] = valid ? s : 0.f;
    }
    __syncthreads();
    #pragma unroll
    for (int it = 0; it < 16; ++it) {       // Ax[m][x] = (c, -s)
        int e = tid + it * 256;
        int mi = e >> 6, xi = e & 63;
        size_t o = (size_t)(m0 + mi) * NN + (g0 + xi);
        Ax_r[o] = f2bf(lc[mi][xi]);
        Ax_i[o] = f2bf(-ls[mi][xi]);
    }
    #pragma unroll
    for (int it = 0; it < 16; ++it) {       // AxTc[x][m] = (c, +s)
        int e = tid + it * 256;
        int xi = e >> 6, mi = e & 63;
        size_t o = (size_t)(g0 + xi) * MSTR + (m0 + mi);
        AxT_r[o] = f2bf(lc[mi][xi]);
        AxT_i[o] = f2bf(ls[mi][xi]);
    }
    __syncthreads();

    #pragma unroll
    for (int it = 0; it < 16; ++it) {
        int e = tid + it * 256;
        int mi = e >> 6, gi = e & 63;
        float c, s;
        phase_cs(kyv[mi], gval(g0 + gi), &c, &s);
        bool valid = (m0 + mi) < MREAL;
        lc[mi][gi] = valid ? c : 0.f;
        ls[mi][gi] = valid ? s : 0.f;
    }
    __syncthreads();
    #pragma unroll
    for (int it = 0; it < 16; ++it) {       // AyT[y][m] = (c, +s) = conj(Ay)
        int e = tid + it * 256;
        int yi = e >> 6, mi = e & 63;
        size_t o = (size_t)(g0 + yi) * MSTR + (m0 + mi);
        AyT_r[o] = f2bf(lc[mi][yi]);
        AyT_i[o] = f2bf(ls[mi][yi]);
    }
}

// ============ conv_img: inp float2 [bc][x][y] -> imgT bf16 [bc][y][x] ============
__global__ __launch_bounds__(256) void conv_img(
    const float* __restrict__ inp,
    unsigned short* __restrict__ iT_r, unsigned short* __restrict__ iT_i)
{
    __shared__ __align__(16) float2 t[64][65];
    const int tid = threadIdx.x;
    const int x0 = blockIdx.x * 64, y0 = blockIdx.y * 64, bc = blockIdx.z;
    const float2* ip = (const float2*)inp;
    #pragma unroll
    for (int it = 0; it < 16; ++it) {
        int e = tid + it * 256;
        int r = e >> 6, c = e & 63;
        t[r][c] = ip[((size_t)bc * NN + (x0 + r)) * NN + (y0 + c)];
    }
    __syncthreads();
    #pragma unroll
    for (int it = 0; it < 16; ++it) {
        int e = tid + it * 256;
        int yy = e >> 6, xx = e & 63;
        float2 v = t[xx][yy];
        size_t o = ((size_t)bc * NN + (y0 + yy)) * NN + (x0 + xx);
        iT_r[o] = f2bf(v.x);
        iT_i[o] = f2bf(v.y);
    }
}

// ============ fwd_gemm: 64y x 128m tile, BK=64, fused Ay-reduce, XCD swizzle ============
__global__ __launch_bounds__(256) void fwd_gemm(
    const unsigned short* __restrict__ iT_r, const unsigned short* __restrict__ iT_i,
    const unsigned short* __restrict__ Ax_r, const unsigned short* __restrict__ Ax_i,
    const unsigned short* __restrict__ AyT_r, const unsigned short* __restrict__ AyT_i,
    float2* __restrict__ partial1)
{
    __shared__ __align__(16) unsigned short Ar[64][72],  Ai[64][72];
    __shared__ __align__(16) unsigned short Br[128][72], Bi[128][72];
    __shared__ __align__(16) float2 redbuf[2][128];

    const int tid = threadIdx.x;
    const int bid = blockIdx.x;
    const int nid = (bid & 7) * 235 + (bid >> 3);
    const int mt  = nid / 40;
    const int r40 = nid - mt * 40;
    const int yt  = r40 % 5;
    const int bc  = r40 / 5;
    const int m0  = mt * 128;
    const int y0  = yt * 64;

    float4_t accR[2][4], accI[2][4];
    #pragma unroll
    for (int i = 0; i < 2; ++i)
        #pragma unroll
        for (int j = 0; j < 4; ++j) { accR[i][j] = (float4_t)0.f; accI[i][j] = (float4_t)0.f; }

    const int lane = tid & 63, wid = tid >> 6;
    const int wy = wid & 1, wm = wid >> 1;
    const int ar = lane & 15, kb = lane >> 4;

    for (int x0 = 0; x0 < NN; x0 += 64) {
        #pragma unroll
        for (int it = 0; it < 2; ++it) {
            int e = tid + it * 256;
            int row = e >> 3, gr = e & 7;
            size_t o = ((size_t)bc * NN + (y0 + row)) * NN + x0 + gr * 8;
            *(short8_t*)&Ar[row][gr * 8] = *(const short8_t*)(iT_r + o);
            *(short8_t*)&Ai[row][gr * 8] = *(const short8_t*)(iT_i + o);
        }
        #pragma unroll
        for (int it = 0; it < 4; ++it) {
            int e = tid + it * 256;
            int row = e >> 3, gr = e & 7;
            size_t o = (size_t)(m0 + row) * NN + x0 + gr * 8;
            *(short8_t*)&Br[row][gr * 8] = *(const short8_t*)(Ax_r + o);
            *(short8_t*)&Bi[row][gr * 8] = *(const short8_t*)(Ax_i + o);
        }
        __syncthreads();

        #pragma unroll
        for (int ks = 0; ks < 2; ++ks) {
            short8_t a_r[2], a_i[2], a_n[2], b_r[4], b_i[4];
            #pragma unroll
            for (int iy = 0; iy < 2; ++iy) {
                int rr = wy * 32 + iy * 16 + ar;
                a_r[iy] = *(const short8_t*)&Ar[rr][ks * 32 + kb * 8];
                a_i[iy] = *(const short8_t*)&Ai[rr][ks * 32 + kb * 8];
                a_n[iy] = neg8(a_i[iy]);
            }
            #pragma unroll
            for (int jm = 0; jm < 4; ++jm) {
                int cc = wm * 64 + jm * 16 + ar;
                b_r[jm] = *(const short8_t*)&Br[cc][ks * 32 + kb * 8];
                b_i[jm] = *(const short8_t*)&Bi[cc][ks * 32 + kb * 8];
            }
            #pragma unroll
            for (int iy = 0; iy < 2; ++iy)
                #pragma unroll
                for (int jm = 0; jm < 4; ++jm) {
                    accR[iy][jm] = __builtin_amdgcn_mfma_f32_16x16x32_bf16(a_r[iy], b_r[jm], accR[iy][jm], 0, 0, 0);
                    accR[iy][jm] = __builtin_amdgcn_mfma_f32_16x16x32_bf16(a_n[iy], b_i[jm], accR[iy][jm], 0, 0, 0);
                    accI[iy][jm] = __builtin_amdgcn_mfma_f32_16x16x32_bf16(a_r[iy], b_i[jm], accI[iy][jm], 0, 0, 0);
                    accI[iy][jm] = __builtin_amdgcn_mfma_f32_16x16x32_bf16(a_i[iy], b_r[jm], accI[iy][jm], 0, 0, 0);
                }
        }
        __syncthreads();
    }

    #pragma unroll
    for (int jm = 0; jm < 4; ++jm) {
        float sr = 0.f, si = 0.f;
        int m = m0 + wm * 64 + jm * 16 + ar;
        #pragma unroll
        for (int iy = 0; iy < 2; ++iy)
            #pragma unroll
            for (int q = 0; q < 4; ++q) {
                int y = y0 + wy * 32 + iy * 16 + kb * 4 + q;
                float c  = bf2f(AyT_r[(size_t)y * MSTR + m]);
                float sy = bf2f(AyT_i[(size_t)y * MSTR + m]);
                float Tr = accR[iy][jm][q], Ti = accI[iy][jm][q];
                sr += Tr * c + Ti * sy;
                si += Ti * c - Tr * sy;
            }
        sr += __shfl_xor(sr, 16); sr += __shfl_xor(sr, 32);
        si += __shfl_xor(si, 16); si += __shfl_xor(si, 32);
        if ((lane & 48) == 0)
            redbuf[wy][wm * 64 + jm * 16 + ar] = make_float2(sr, si);
    }
    __syncthreads();
    if (tid < 128) {
        float2 a = redbuf[0][tid], b = redbuf[1][tid];
        int m = m0 + tid;
        if (m < MREAL)
            partial1[((size_t)bc * 5 + yt) * P1STR + m] = make_float2(a.x + b.x, a.y + b.y);
    }
}

// ============ reduce_ksp ============
__global__ void reduce_ksp(const float2* __restrict__ partial1,
                           float2* __restrict__ ksp)
{
    int mp = blockIdx.x * 256 + threadIdx.x;   // grid (24, 8)
    int bc = blockIdx.y;
    float2 r = make_float2(0.f, 0.f);
    if (mp < MREAL) {
        #pragma unroll
        for (int yt = 0; yt < 5; ++yt) {
            float2 v = partial1[((size_t)bc * 5 + yt) * P1STR + mp];
            r.x += v.x; r.y += v.y;
        }
    }
    ksp[(size_t)bc * MSTR + mp] = r;
}

// ============ gen_U: U[bc][y][m] = ksp[bc][m] * conjAy[m][y] (bf16 planes) ============
__global__ __launch_bounds__(256) void gen_U(
    const unsigned short* __restrict__ AyT_r, const unsigned short* __restrict__ AyT_i,
    const float2* __restrict__ ksp,
    unsigned short* __restrict__ U_r, unsigned short* __restrict__ U_i)
{
    const int tid = threadIdx.x;
    const int m0 = blockIdx.x * 2048 + tid * 8;   // grid.x = 3 (MSTR/2048)
    const int y  = blockIdx.y;
    const int bc = blockIdx.z;

    short8_t yr = *(const short8_t*)(AyT_r + (size_t)y * MSTR + m0);
    short8_t yi = *(const short8_t*)(AyT_i + (size_t)y * MSTR + m0);
    const float2* kp = ksp + (size_t)bc * MSTR + m0;
    short8_t ur, ui;
    #pragma unroll
    for (int j = 0; j < 8; ++j) {
        float2 k = kp[j];
        float cr = bf2f((unsigned short)yr[j]);
        float ci = bf2f((unsigned short)yi[j]);
        ur[j] = (short)f2bf(k.x * cr - k.y * ci);
        ui[j] = (short)f2bf(k.x * ci + k.y * cr);
    }
    size_t o = ((size_t)bc * NN + y) * MSTR + m0;
    *(short8_t*)(U_r + o) = ur;
    *(short8_t*)(U_i + o) = ui;
}

// ============ adj_gemm: out-tile 64x x 64y, BK=64, split-K ============
// PREU=1: B staged from precomputed U.  PREU=0: ksp*conjAy computed in-staging.
template<int FP32P, int PREU>
__global__ __launch_bounds__(256) void adj_gemm(
    const unsigned short* __restrict__ AxT_r, const unsigned short* __restrict__ AxT_i,
    const unsigned short* __restrict__ Bp_r, const unsigned short* __restrict__ Bp_i,
    const float2* __restrict__ ksp, void* __restrict__ partial2)
{
    __shared__ __align__(16) unsigned short Ar[64][72], Ai[64][72];
    __shared__ __align__(16) unsigned short Br[64][72], Bi[64][72];
    __shared__ __align__(16) float2 kspl[PREU ? 1 : CHUNKM];

    const int tid = threadIdx.x;
    // grid = 800 = (8 bc * SKADJ) * 25 xy ; XCD-chunked: same (bc,sk) contiguous per XCD
    const int bid = blockIdx.x;
    const int nid = (bid & 7) * 100 + (bid >> 3);
    const int bcsk = nid / 25;
    const int xy = nid - bcsk * 25;
    const int xt = xy / 5, yt = xy % 5;
    const int bc = bcsk & 7, sk = bcsk >> 3;
    const int x0 = xt * 64, y0 = yt * 64;
    const int kbeg = sk * CHUNKM;

    if (!PREU) {
        #pragma unroll
        for (int it = 0; it < CHUNKM / 256; ++it)
            kspl[tid + it * 256] = ksp[(size_t)bc * MSTR + kbeg + tid + it * 256];
        __syncthreads();
    }

    float4_t accR[2][2], accI[2][2];
    #pragma unroll
    for (int i = 0; i < 2; ++i)
        #pragma unroll
        for (int j = 0; j < 2; ++j) { accR[i][j] = (float4_t)0.f; accI[i][j] = (float4_t)0.f; }

    const int lane = tid & 63, wid = tid >> 6;
    const int wx = wid >> 1, wyy = wid & 1;
    const int ar = lane & 15, kb = lane >> 4;

    for (int mk = 0; mk < CHUNKM; mk += 64) {
        // stage A = conjAx (AxTc stored (c,+s))
        #pragma unroll
        for (int it = 0; it < 2; ++it) {
            int e = tid + it * 256;
            int row = e >> 3, gr = e & 7;
            size_t o = (size_t)(x0 + row) * MSTR + kbeg + mk + gr * 8;
            *(short8_t*)&Ar[row][gr * 8] = *(const short8_t*)(AxT_r + o);
            *(short8_t*)&Ai[row][gr * 8] = *(const short8_t*)(AxT_i + o);
        }
        // stage B
        #pragma unroll
        for (int it = 0; it < 2; ++it) {
            int e = tid + it * 256;
            int row = e >> 3, gr = e & 7;
            if (PREU) {
                size_t o = ((size_t)bc * NN + (y0 + row)) * MSTR + kbeg + mk + gr * 8;
                *(short8_t*)&Br[row][gr * 8] = *(const short8_t*)(Bp_r + o);
                *(short8_t*)&Bi[row][gr * 8] = *(const short8_t*)(Bp_i + o);
            } else {
                size_t o = (size_t)(y0 + row) * MSTR + kbeg + mk + gr * 8;
                short8_t yr = *(const short8_t*)(Bp_r + o);
                short8_t yi = *(const short8_t*)(Bp_i + o);
                short8_t br, bi2;
                #pragma unroll
                for (int j = 0; j < 8; ++j) {
                    float2 k = kspl[mk + gr * 8 + j];
                    float cr = bf2f((unsigned short)yr[j]);
                    float ci = bf2f((unsigned short)yi[j]);
                    br[j]  = (short)f2bf(k.x * cr - k.y * ci);
                    bi2[j] = (short)f2bf(k.x * ci + k.y * cr);
                }
                *(short8_t*)&Br[row][gr * 8] = br;
                *(short8_t*)&Bi[row][gr * 8] = bi2;
            }
        }
        __syncthreads();

        #pragma unroll
        for (int ks = 0; ks < 2; ++ks) {
            short8_t a_r[2], a_i[2], a_n[2], b_r[2], b_i[2];
            #pragma unroll
            for (int ix = 0; ix < 2; ++ix) {
                int rr = wx * 32 + ix * 16 + ar;
                a_r[ix] = *(const short8_t*)&Ar[rr][ks * 32 + kb * 8];
                a_i[ix] = *(const short8_t*)&Ai[rr][ks * 32 + kb * 8];
                a_n[ix] = neg8(a_i[ix]);
            }
            #pragma unroll
            for (int jy = 0; jy < 2; ++jy) {
                int cc = wyy * 32 + jy * 16 + ar;
                b_r[jy] = *(const short8_t*)&Br[cc][ks * 32 + kb * 8];
                b_i[jy] = *(const short8_t*)&Bi[cc][ks * 32 + kb * 8];
            }
            #pragma unroll
            for (int ix = 0; ix < 2; ++ix)
                #pragma unroll
                for (int jy = 0; jy < 2; ++jy) {
                    accR[ix][jy] = __builtin_amdgcn_mfma_f32_16x16x32_bf16(a_r[ix], b_r[jy], accR[ix][jy], 0, 0, 0);
                    accR[ix][jy] = __builtin_amdgcn_mfma_f32_16x16x32_bf16(a_n[ix], b_i[jy], accR[ix][jy], 0, 0, 0);
                    accI[ix][jy] = __builtin_amdgcn_mfma_f32_16x16x32_bf16(a_r[ix], b_i[jy], accI[ix][jy], 0, 0, 0);
                    accI[ix][jy] = __builtin_amdgcn_mfma_f32_16x16x32_bf16(a_i[ix], b_r[jy], accI[ix][jy], 0, 0, 0);
                }
        }
        __syncthreads();
    }

    #pragma unroll
    for (int ix = 0; ix < 2; ++ix)
        #pragma unroll
        for (int jy = 0; jy < 2; ++jy)
            #pragma unroll
            for (int q = 0; q < 4; ++q) {
                int x = x0 + wx * 32 + ix * 16 + kb * 4 + q;
                int y = y0 + wyy * 32 + jy * 16 + ar;
                size_t o = (((size_t)sk * BCC + bc) * NN + x) * NN + y;
                float vr = accR[ix][jy][q], vi = accI[ix][jy][q];
                if (FP32P) {
                    ((float2*)partial2)[o] = make_float2(vr, vi);
                } else {
                    ((unsigned*)partial2)[o] =
                        (unsigned)f2bf(vr) | ((unsigned)f2bf(vi) << 16);
                }
            }
}

// ============ reduce_out ============
template<int FP32P>
__global__ void reduce_out(const void* __restrict__ partial2,
                           float2* __restrict__ out)
{
    size_t total = (size_t)BCC * NN * NN;
    size_t idx = (size_t)blockIdx.x * 256 + threadIdx.x;
    if (idx >= total) return;
    float2 r = make_float2(0.f, 0.f);
    #pragma unroll
    for (int s = 0; s < SKADJ; ++s) {
        if (FP32P) {
            float2 v = ((const float2*)partial2)[s * total + idx];
            r.x += v.x; r.y += v.y;
        } else {
            unsigned u = ((const unsigned*)partial2)[s * total + idx];
            r.x += bf2f((unsigned short)(u & 0xffff));
            r.y += bf2f((unsigned short)(u >> 16));
        }
    }
    out[idx] = r;
}

// ============ host ============
extern "C" void kernel_launch(void* const* d_in, const int* in_sizes, int n_in,
                              void* d_out, int out_size, void* d_ws, size_t ws_size,
                              hipStream_t stream)
{
    const float* inp  = (const float*)d_in[0];
    const float* traj = (const float*)d_in[1];

    char* ws = (char*)d_ws;
    const size_t PL = (size_t)NN * MSTR * 2;           // 3,932,160 B per bf16 plane
    unsigned short* AxT_r = (unsigned short*)(ws);
    unsigned short* AxT_i = (unsigned short*)(ws + PL);
    unsigned short* AyT_r = (unsigned short*)(ws + 2 * PL);
    unsigned short* AyT_i = (unsigned short*)(ws + 3 * PL);
    float2* ksp = (float2*)(ws + 4 * PL);
    const size_t KSPB = (size_t)BCC * MSTR * 8;        // 393,216
    const size_t BASE = 4 * PL + KSPB;                 // 16,121,856
    char* rb = ws + BASE;
    // fwd phase (dead after reduce_ksp; aliases U region):
    unsigned short* Ax_r = (unsigned short*)(rb);
    unsigned short* Ax_i = (unsigned short*)(rb + PL);
    const size_t ITP = (size_t)BCC * NN * NN * 2;      // 1,638,400 per plane
    unsigned short* iT_r = (unsigned short*)(rb + 2 * PL);
    unsigned short* iT_i = (unsigned short*)(rb + 2 * PL + ITP);
    float2* partial1 = (float2*)(rb + 2 * PL + 2 * ITP);
    // adj phase:
    const size_t UPL = (size_t)BCC * NN * MSTR * 2;    // 31,457,280 per U plane
    unsigned short* U_r = (unsigned short*)(rb);
    unsigned short* U_i = (unsigned short*)(rb + UPL);
    const size_t ADJ_F32 = (size_t)SKADJ * BCC * NN * NN * 8;   // 26,214,400
    const size_t ADJ_B16 = ADJ_F32 / 2;

    gen_A<<<dim3(96, 5), 256, 0, stream>>>(traj, Ax_r, Ax_i, AxT_r, AxT_i, AyT_r, AyT_i);
    conv_img<<<dim3(5, 5, BCC), 256, 0, stream>>>(inp, iT_r, iT_i);
    fwd_gemm<<<dim3(1880), 256, 0, stream>>>(iT_r, iT_i, Ax_r, Ax_i, AyT_r, AyT_i, partial1);
    reduce_ksp<<<dim3(24, BCC), 256, 0, stream>>>(partial1, ksp);

    size_t total = (size_t)BCC * NN * NN;
    int rblocks = (int)((total + 255) / 256);

    if (ws_size >= BASE + 2 * UPL + ADJ_F32) {
        void* partial2 = (void*)(rb + 2 * UPL);
        gen_U<<<dim3(3, NN, BCC), 256, 0, stream>>>(AyT_r, AyT_i, ksp, U_r, U_i);
        adj_gemm<1,1><<<dim3(800), 256, 0, stream>>>(AxT_r, AxT_i, U_r, U_i, ksp, partial2);
        reduce_out<1><<<rblocks, 256, 0, stream>>>(partial2, (float2*)d_out);
    } else if (ws_size >= BASE + 2 * UPL + ADJ_B16) {
        void* partial2 = (void*)(rb + 2 * UPL);
        gen_U<<<dim3(3, NN, BCC), 256, 0, stream>>>(AyT_r, AyT_i, ksp, U_r, U_i);
        adj_gemm<0,1><<<dim3(800), 256, 0, stream>>>(AxT_r, AxT_i, U_r, U_i, ksp, partial2);
        reduce_out<0><<<rblocks, 256, 0, stream>>>(partial2, (float2*)d_out);
    } else if (ws_size >= BASE + ADJ_F32) {
        void* partial2 = (void*)rb;
        adj_gemm<1,0><<<dim3(800), 256, 0, stream>>>(AxT_r, AxT_i, AyT_r, AyT_i, ksp, partial2);
        reduce_out<1><<<rblocks, 256, 0, stream>>>(partial2, (float2*)d_out);
    } else {
        void* partial2 = (void*)rb;
        adj_gemm<0,0><<<dim3(800), 256, 0, stream>>>(AxT_r, AxT_i, AyT_r, AyT_i, ksp, partial2);
        reduce_out<0><<<rblocks, 256, 0, stream>>>(partial2, (float2*)d_out);
    }
}

// Round 5
// 144.297 us; speedup vs baseline: 1.9474x; 1.9474x over previous
//
#include <hip/hip_runtime.h>
#include <math.h>

// NUFFT roundtrip on bf16 MFMA (16x16x32), fp32 accumulate.
// fwd:  D[y][m] = sum_x imgT[y][x] * Ax[m][x];  ksp[m] = sum_y D[y][m]*Ay[m][y] (fused epi)
// adj:  out[x][y] = sum_m conjAx[x][m] * U[m][y],  U = ksp * conjAy (gen_U), split-K=8,
//       reg-staged 2-phase prefetch in both GEMMs (loads in flight across the MFMA phase).

#define NN      320
#define BCC     8
#define MREAL   6008
#define MSTR    6144          // padded m stride, 96*64
#define MT1     47            // fwd m-tiles of 128 -> 6016 cols
#define P1STR   6016
#define SKADJ   8
#define CHUNKM  (MSTR / SKADJ)   // 768
#define NADJB   1600             // (8 bc * SKADJ) * 25 xy
#define TWOPI   6.283185307179586f

typedef __attribute__((ext_vector_type(8))) short short8_t;
typedef __attribute__((ext_vector_type(4))) float float4_t;

__device__ __forceinline__ unsigned short f2bf(float f) {
    union { float f; unsigned u; } v; v.f = f;
    unsigned r = v.u + 0x7fff + ((v.u >> 16) & 1);
    return (unsigned short)(r >> 16);
}
__device__ __forceinline__ float bf2f(unsigned short h) {
    union { unsigned u; float f; } v; v.u = ((unsigned)h) << 16;
    return v.f;
}
__device__ __forceinline__ short8_t neg8(short8_t v) {
    short8_t r;
    #pragma unroll
    for (int i = 0; i < 8; ++i) r[i] = v[i] ^ (short)0x8000;
    return r;
}
__device__ __forceinline__ float gval(int i) { return (float)(i - NN/2); }

__device__ __forceinline__ void phase_cs(float k, float g, float* c, float* s) {
    float rev = k * (g * (1.0f / (float)NN));
    rev -= rintf(rev);
    float th = rev * TWOPI;
    __sincosf(th, s, c);
}

// ============ gen_A: build Ax[m][x], AxTc[x][m], AyT[y][m] ============
__global__ __launch_bounds__(256) void gen_A(
    const float* __restrict__ traj,
    unsigned short* __restrict__ Ax_r, unsigned short* __restrict__ Ax_i,
    unsigned short* __restrict__ AxT_r, unsigned short* __restrict__ AxT_i,
    unsigned short* __restrict__ AyT_r, unsigned short* __restrict__ AyT_i)
{
    __shared__ __align__(16) float lc[64][65];
    __shared__ __align__(16) float ls[64][65];
    __shared__ float kxv[64], kyv[64];
    const int tid = threadIdx.x;
    const int m0 = blockIdx.x * 64;
    const int g0 = blockIdx.y * 64;

    if (tid < 64) {
        int m = m0 + tid;
        kxv[tid] = (m < MREAL) ? traj[2*m]     : 0.f;
        kyv[tid] = (m < MREAL) ? traj[2*m + 1] : 0.f;
    }
    __syncthreads();

    #pragma unroll
    for (int it = 0; it < 16; ++it) {
        int e = tid + it * 256;
        int mi = e >> 6, gi = e & 63;
        float c, s;
        phase_cs(kxv[mi], gval(g0 + gi), &c, &s);
        bool valid = (m0 + mi) < MREAL;
        lc[mi][gi] = valid ? c : 0.f;
        ls[mi][gi] = valid ? s : 0.f;
    }
    __syncthreads();
    #pragma unroll
    for (int it = 0; it < 16; ++it) {       // Ax[m][x] = (c, -s)
        int e = tid + it * 256;
        int mi = e >> 6, xi = e & 63;
        size_t o = (size_t)(m0 + mi) * NN + (g0 + xi);
        Ax_r[o] = f2bf(lc[mi][xi]);
        Ax_i[o] = f2bf(-ls[mi][xi]);
    }
    #pragma unroll
    for (int it = 0; it < 16; ++it) {       // AxTc[x][m] = (c, +s)
        int e = tid + it * 256;
        int xi = e >> 6, mi = e & 63;
        size_t o = (size_t)(g0 + xi) * MSTR + (m0 + mi);
        AxT_r[o] = f2bf(lc[mi][xi]);
        AxT_i[o] = f2bf(ls[mi][xi]);
    }
    __syncthreads();

    #pragma unroll
    for (int it = 0; it < 16; ++it) {
        int e = tid + it * 256;
        int mi = e >> 6, gi = e & 63;
        float c, s;
        phase_cs(kyv[mi], gval(g0 + gi), &c, &s);
        bool valid = (m0 + mi) < MREAL;
        lc[mi][gi] = valid ? c : 0.f;
        ls[mi][gi] = valid ? s : 0.f;
    }
    __syncthreads();
    #pragma unroll
    for (int it = 0; it < 16; ++it) {       // AyT[y][m] = (c, +s) = conj(Ay)
        int e = tid + it * 256;
        int yi = e >> 6, mi = e & 63;
        size_t o = (size_t)(g0 + yi) * MSTR + (m0 + mi);
        AyT_r[o] = f2bf(lc[mi][yi]);
        AyT_i[o] = f2bf(ls[mi][yi]);
    }
}

// ============ conv_img: inp float2 [bc][x][y] -> imgT bf16 [bc][y][x] ============
__global__ __launch_bounds__(256) void conv_img(
    const float* __restrict__ inp,
    unsigned short* __restrict__ iT_r, unsigned short* __restrict__ iT_i)
{
    __shared__ __align__(16) float2 t[64][65];
    const int tid = threadIdx.x;
    const int x0 = blockIdx.x * 64, y0 = blockIdx.y * 64, bc = blockIdx.z;
    const float2* ip = (const float2*)inp;
    #pragma unroll
    for (int it = 0; it < 16; ++it) {
        int e = tid + it * 256;
        int r = e >> 6, c = e & 63;
        t[r][c] = ip[((size_t)bc * NN + (x0 + r)) * NN + (y0 + c)];
    }
    __syncthreads();
    #pragma unroll
    for (int it = 0; it < 16; ++it) {
        int e = tid + it * 256;
        int yy = e >> 6, xx = e & 63;
        float2 v = t[xx][yy];
        size_t o = ((size_t)bc * NN + (y0 + yy)) * NN + (x0 + xx);
        iT_r[o] = f2bf(v.x);
        iT_i[o] = f2bf(v.y);
    }
}

// ============ fwd_gemm: 64y x 128m tile, BK=64, reg-prefetch, fused Ay-reduce ============
__global__ __launch_bounds__(256) void fwd_gemm(
    const unsigned short* __restrict__ iT_r, const unsigned short* __restrict__ iT_i,
    const unsigned short* __restrict__ Ax_r, const unsigned short* __restrict__ Ax_i,
    const unsigned short* __restrict__ AyT_r, const unsigned short* __restrict__ AyT_i,
    float2* __restrict__ partial1)
{
    __shared__ __align__(16) unsigned short Ar[64][72],  Ai[64][72];
    __shared__ __align__(16) unsigned short Br[128][72], Bi[128][72];
    __shared__ __align__(16) float2 redbuf[2][128];

    const int tid = threadIdx.x;
    const int bid = blockIdx.x;
    const int nid = (bid & 7) * 235 + (bid >> 3);
    const int mt  = nid / 40;
    const int r40 = nid - mt * 40;
    const int yt  = r40 % 5;
    const int bc  = r40 / 5;
    const int m0  = mt * 128;
    const int y0  = yt * 64;

    float4_t accR[2][4], accI[2][4];
    #pragma unroll
    for (int i = 0; i < 2; ++i)
        #pragma unroll
        for (int j = 0; j < 4; ++j) { accR[i][j] = (float4_t)0.f; accI[i][j] = (float4_t)0.f; }

    const int lane = tid & 63, wid = tid >> 6;
    const int wy = wid & 1, wm = wid >> 1;
    const int ar = lane & 15, kb = lane >> 4;

    const int row = tid >> 3;            // 0..31
    const int gr  = (tid & 7) * 8;       // 0..56

    // global base offsets (advance by x0 along NN-stride rows)
    const size_t ga0 = ((size_t)bc * NN + (y0 + row))      * NN + gr;
    const size_t ga1 = ((size_t)bc * NN + (y0 + row + 32)) * NN + gr;
    size_t gb[4];
    #pragma unroll
    for (int it = 0; it < 4; ++it) gb[it] = (size_t)(m0 + row + it * 32) * NN + gr;

    short8_t pAr0, pAr1, pAi0, pAi1;
    short8_t pBr0, pBr1, pBr2, pBr3, pBi0, pBi1, pBi2, pBi3;

#define FLOAD(xo) do { \
    pAr0 = *(const short8_t*)(iT_r + ga0 + (xo)); \
    pAi0 = *(const short8_t*)(iT_i + ga0 + (xo)); \
    pAr1 = *(const short8_t*)(iT_r + ga1 + (xo)); \
    pAi1 = *(const short8_t*)(iT_i + ga1 + (xo)); \
    pBr0 = *(const short8_t*)(Ax_r + gb[0] + (xo)); \
    pBi0 = *(const short8_t*)(Ax_i + gb[0] + (xo)); \
    pBr1 = *(const short8_t*)(Ax_r + gb[1] + (xo)); \
    pBi1 = *(const short8_t*)(Ax_i + gb[1] + (xo)); \
    pBr2 = *(const short8_t*)(Ax_r + gb[2] + (xo)); \
    pBi2 = *(const short8_t*)(Ax_i + gb[2] + (xo)); \
    pBr3 = *(const short8_t*)(Ax_r + gb[3] + (xo)); \
    pBi3 = *(const short8_t*)(Ax_i + gb[3] + (xo)); } while (0)

    FLOAD(0);
    for (int x0i = 0; x0i < NN; x0i += 64) {
        *(short8_t*)&Ar[row][gr]       = pAr0;
        *(short8_t*)&Ai[row][gr]       = pAi0;
        *(short8_t*)&Ar[row + 32][gr]  = pAr1;
        *(short8_t*)&Ai[row + 32][gr]  = pAi1;
        *(short8_t*)&Br[row][gr]       = pBr0;
        *(short8_t*)&Bi[row][gr]       = pBi0;
        *(short8_t*)&Br[row + 32][gr]  = pBr1;
        *(short8_t*)&Bi[row + 32][gr]  = pBi1;
        *(short8_t*)&Br[row + 64][gr]  = pBr2;
        *(short8_t*)&Bi[row + 64][gr]  = pBi2;
        *(short8_t*)&Br[row + 96][gr]  = pBr3;
        *(short8_t*)&Bi[row + 96][gr]  = pBi3;
        __syncthreads();

        if (x0i + 64 < NN) FLOAD(x0i + 64);   // prefetch next tile (in flight over MFMA)

        #pragma unroll
        for (int ks = 0; ks < 2; ++ks) {
            short8_t a_r[2], a_i[2], a_n[2], b_r[4], b_i[4];
            #pragma unroll
            for (int iy = 0; iy < 2; ++iy) {
                int rr = wy * 32 + iy * 16 + ar;
                a_r[iy] = *(const short8_t*)&Ar[rr][ks * 32 + kb * 8];
                a_i[iy] = *(const short8_t*)&Ai[rr][ks * 32 + kb * 8];
                a_n[iy] = neg8(a_i[iy]);
            }
            #pragma unroll
            for (int jm = 0; jm < 4; ++jm) {
                int cc = wm * 64 + jm * 16 + ar;
                b_r[jm] = *(const short8_t*)&Br[cc][ks * 32 + kb * 8];
                b_i[jm] = *(const short8_t*)&Bi[cc][ks * 32 + kb * 8];
            }
            #pragma unroll
            for (int iy = 0; iy < 2; ++iy)
                #pragma unroll
                for (int jm = 0; jm < 4; ++jm) {
                    accR[iy][jm] = __builtin_amdgcn_mfma_f32_16x16x32_bf16(a_r[iy], b_r[jm], accR[iy][jm], 0, 0, 0);
                    accR[iy][jm] = __builtin_amdgcn_mfma_f32_16x16x32_bf16(a_n[iy], b_i[jm], accR[iy][jm], 0, 0, 0);
                    accI[iy][jm] = __builtin_amdgcn_mfma_f32_16x16x32_bf16(a_r[iy], b_i[jm], accI[iy][jm], 0, 0, 0);
                    accI[iy][jm] = __builtin_amdgcn_mfma_f32_16x16x32_bf16(a_i[iy], b_r[jm], accI[iy][jm], 0, 0, 0);
                }
        }
        __syncthreads();
    }
#undef FLOAD

    #pragma unroll
    for (int jm = 0; jm < 4; ++jm) {
        float sr = 0.f, si = 0.f;
        int m = m0 + wm * 64 + jm * 16 + ar;
        #pragma unroll
        for (int iy = 0; iy < 2; ++iy)
            #pragma unroll
            for (int q = 0; q < 4; ++q) {
                int y = y0 + wy * 32 + iy * 16 + kb * 4 + q;
                float c  = bf2f(AyT_r[(size_t)y * MSTR + m]);
                float sy = bf2f(AyT_i[(size_t)y * MSTR + m]);
                float Tr = accR[iy][jm][q], Ti = accI[iy][jm][q];
                sr += Tr * c + Ti * sy;
                si += Ti * c - Tr * sy;
            }
        sr += __shfl_xor(sr, 16); sr += __shfl_xor(sr, 32);
        si += __shfl_xor(si, 16); si += __shfl_xor(si, 32);
        if ((lane & 48) == 0)
            redbuf[wy][wm * 64 + jm * 16 + ar] = make_float2(sr, si);
    }
    __syncthreads();
    if (tid < 128) {
        float2 a = redbuf[0][tid], b = redbuf[1][tid];
        int m = m0 + tid;
        if (m < MREAL)
            partial1[((size_t)bc * 5 + yt) * P1STR + m] = make_float2(a.x + b.x, a.y + b.y);
    }
}

// ============ reduce_ksp ============
__global__ void reduce_ksp(const float2* __restrict__ partial1,
                           float2* __restrict__ ksp)
{
    int mp = blockIdx.x * 256 + threadIdx.x;   // grid (24, 8)
    int bc = blockIdx.y;
    float2 r = make_float2(0.f, 0.f);
    if (mp < MREAL) {
        #pragma unroll
        for (int yt = 0; yt < 5; ++yt) {
            float2 v = partial1[((size_t)bc * 5 + yt) * P1STR + mp];
            r.x += v.x; r.y += v.y;
        }
    }
    ksp[(size_t)bc * MSTR + mp] = r;
}

// ============ gen_U: U[bc][y][m] = ksp[bc][m] * conjAy[m][y] ============
__global__ __launch_bounds__(256) void gen_U(
    const unsigned short* __restrict__ AyT_r, const unsigned short* __restrict__ AyT_i,
    const float2* __restrict__ ksp,
    unsigned short* __restrict__ U_r, unsigned short* __restrict__ U_i)
{
    const int tid = threadIdx.x;
    const int m0 = blockIdx.x * 2048 + tid * 8;   // grid.x = 3
    const int y  = blockIdx.y;
    const int bc = blockIdx.z;

    short8_t yr = *(const short8_t*)(AyT_r + (size_t)y * MSTR + m0);
    short8_t yi = *(const short8_t*)(AyT_i + (size_t)y * MSTR + m0);
    const float2* kp = ksp + (size_t)bc * MSTR + m0;
    short8_t ur, ui;
    #pragma unroll
    for (int j = 0; j < 8; ++j) {
        float2 k = kp[j];
        float cr = bf2f((unsigned short)yr[j]);
        float ci = bf2f((unsigned short)yi[j]);
        ur[j] = (short)f2bf(k.x * cr - k.y * ci);
        ui[j] = (short)f2bf(k.x * ci + k.y * cr);
    }
    size_t o = ((size_t)bc * NN + y) * MSTR + m0;
    *(short8_t*)(U_r + o) = ur;
    *(short8_t*)(U_i + o) = ui;
}

// ============ adj_gemm_pre: 64x x 64y tile, BK=64, split-K=8, reg-prefetch ============
template<int FP32P>
__global__ __launch_bounds__(256) void adj_gemm_pre(
    const unsigned short* __restrict__ AxT_r, const unsigned short* __restrict__ AxT_i,
    const unsigned short* __restrict__ U_r, const unsigned short* __restrict__ U_i,
    void* __restrict__ partial2)
{
    __shared__ __align__(16) unsigned short Ar[64][72], Ai[64][72];
    __shared__ __align__(16) unsigned short Br[64][72], Bi[64][72];

    const int tid = threadIdx.x;
    const int bid = blockIdx.x;
    const int nid = (bid & 7) * (NADJB / 8) + (bid >> 3);
    const int bcsk = nid / 25;
    const int xy = nid - bcsk * 25;
    const int xt = xy / 5, yt = xy % 5;
    const int bc = bcsk & 7, sk = bcsk >> 3;
    const int x0 = xt * 64, y0 = yt * 64;
    const int kbeg = sk * CHUNKM;

    float4_t accR[2][2], accI[2][2];
    #pragma unroll
    for (int i = 0; i < 2; ++i)
        #pragma unroll
        for (int j = 0; j < 2; ++j) { accR[i][j] = (float4_t)0.f; accI[i][j] = (float4_t)0.f; }

    const int lane = tid & 63, wid = tid >> 6;
    const int wx = wid >> 1, wyy = wid & 1;
    const int ar = lane & 15, kb = lane >> 4;

    const int row = tid >> 3;            // 0..31
    const int gr  = (tid & 7) * 8;

    const size_t ao0 = (size_t)(x0 + row)      * MSTR + kbeg + gr;
    const size_t ao1 = (size_t)(x0 + row + 32) * MSTR + kbeg + gr;
    const size_t bo0 = ((size_t)bc * NN + (y0 + row))      * MSTR + kbeg + gr;
    const size_t bo1 = ((size_t)bc * NN + (y0 + row + 32)) * MSTR + kbeg + gr;

    short8_t pAr0, pAr1, pAi0, pAi1, pBr0, pBr1, pBi0, pBi1;

#define ALOAD(mk) do { \
    pAr0 = *(const short8_t*)(AxT_r + ao0 + (mk)); \
    pAi0 = *(const short8_t*)(AxT_i + ao0 + (mk)); \
    pAr1 = *(const short8_t*)(AxT_r + ao1 + (mk)); \
    pAi1 = *(const short8_t*)(AxT_i + ao1 + (mk)); \
    pBr0 = *(const short8_t*)(U_r + bo0 + (mk)); \
    pBi0 = *(const short8_t*)(U_i + bo0 + (mk)); \
    pBr1 = *(const short8_t*)(U_r + bo1 + (mk)); \
    pBi1 = *(const short8_t*)(U_i + bo1 + (mk)); } while (0)

    ALOAD(0);
    for (int mk = 0; mk < CHUNKM; mk += 64) {
        *(short8_t*)&Ar[row][gr]      = pAr0;
        *(short8_t*)&Ai[row][gr]      = pAi0;
        *(short8_t*)&Ar[row + 32][gr] = pAr1;
        *(short8_t*)&Ai[row + 32][gr] = pAi1;
        *(short8_t*)&Br[row][gr]      = pBr0;
        *(short8_t*)&Bi[row][gr]      = pBi0;
        *(short8_t*)&Br[row + 32][gr] = pBr1;
        *(short8_t*)&Bi[row + 32][gr] = pBi1;
        __syncthreads();

        if (mk + 64 < CHUNKM) ALOAD(mk + 64);   // prefetch next tile

        #pragma unroll
        for (int ks = 0; ks < 2; ++ks) {
            short8_t a_r[2], a_i[2], a_n[2], b_r[2], b_i[2];
            #pragma unroll
            for (int ix = 0; ix < 2; ++ix) {
                int rr = wx * 32 + ix * 16 + ar;
                a_r[ix] = *(const short8_t*)&Ar[rr][ks * 32 + kb * 8];
                a_i[ix] = *(const short8_t*)&Ai[rr][ks * 32 + kb * 8];
                a_n[ix] = neg8(a_i[ix]);
            }
            #pragma unroll
            for (int jy = 0; jy < 2; ++jy) {
                int cc = wyy * 32 + jy * 16 + ar;
                b_r[jy] = *(const short8_t*)&Br[cc][ks * 32 + kb * 8];
                b_i[jy] = *(const short8_t*)&Bi[cc][ks * 32 + kb * 8];
            }
            #pragma unroll
            for (int ix = 0; ix < 2; ++ix)
                #pragma unroll
                for (int jy = 0; jy < 2; ++jy) {
                    accR[ix][jy] = __builtin_amdgcn_mfma_f32_16x16x32_bf16(a_r[ix], b_r[jy], accR[ix][jy], 0, 0, 0);
                    accR[ix][jy] = __builtin_amdgcn_mfma_f32_16x16x32_bf16(a_n[ix], b_i[jy], accR[ix][jy], 0, 0, 0);
                    accI[ix][jy] = __builtin_amdgcn_mfma_f32_16x16x32_bf16(a_r[ix], b_i[jy], accI[ix][jy], 0, 0, 0);
                    accI[ix][jy] = __builtin_amdgcn_mfma_f32_16x16x32_bf16(a_i[ix], b_r[jy], accI[ix][jy], 0, 0, 0);
                }
        }
        __syncthreads();
    }
#undef ALOAD

    #pragma unroll
    for (int ix = 0; ix < 2; ++ix)
        #pragma unroll
        for (int jy = 0; jy < 2; ++jy)
            #pragma unroll
            for (int q = 0; q < 4; ++q) {
                int x = x0 + wx * 32 + ix * 16 + kb * 4 + q;
                int y = y0 + wyy * 32 + jy * 16 + ar;
                size_t o = (((size_t)sk * BCC + bc) * NN + x) * NN + y;
                float vr = accR[ix][jy][q], vi = accI[ix][jy][q];
                if (FP32P) {
                    ((float2*)partial2)[o] = make_float2(vr, vi);
                } else {
                    ((unsigned*)partial2)[o] =
                        (unsigned)f2bf(vr) | ((unsigned)f2bf(vi) << 16);
                }
            }
}

// ============ adj_gemm_fb: fallback (no U precompute), correctness path ============
template<int FP32P>
__global__ __launch_bounds__(256) void adj_gemm_fb(
    const unsigned short* __restrict__ AxT_r, const unsigned short* __restrict__ AxT_i,
    const unsigned short* __restrict__ AyT_r, const unsigned short* __restrict__ AyT_i,
    const float2* __restrict__ ksp, void* __restrict__ partial2)
{
    __shared__ __align__(16) unsigned short Ar[64][72], Ai[64][72];
    __shared__ __align__(16) unsigned short Br[64][72], Bi[64][72];
    __shared__ __align__(16) float2 kspl[CHUNKM];

    const int tid = threadIdx.x;
    const int bid = blockIdx.x;
    const int nid = (bid & 7) * (NADJB / 8) + (bid >> 3);
    const int bcsk = nid / 25;
    const int xy = nid - bcsk * 25;
    const int xt = xy / 5, yt = xy % 5;
    const int bc = bcsk & 7, sk = bcsk >> 3;
    const int x0 = xt * 64, y0 = yt * 64;
    const int kbeg = sk * CHUNKM;

    #pragma unroll
    for (int it = 0; it < CHUNKM / 256; ++it)
        kspl[tid + it * 256] = ksp[(size_t)bc * MSTR + kbeg + tid + it * 256];
    __syncthreads();

    float4_t accR[2][2], accI[2][2];
    #pragma unroll
    for (int i = 0; i < 2; ++i)
        #pragma unroll
        for (int j = 0; j < 2; ++j) { accR[i][j] = (float4_t)0.f; accI[i][j] = (float4_t)0.f; }

    const int lane = tid & 63, wid = tid >> 6;
    const int wx = wid >> 1, wyy = wid & 1;
    const int ar = lane & 15, kb = lane >> 4;

    for (int mk = 0; mk < CHUNKM; mk += 64) {
        #pragma unroll
        for (int it = 0; it < 2; ++it) {
            int e = tid + it * 256;
            int row = e >> 3, gr = e & 7;
            size_t o = (size_t)(x0 + row) * MSTR + kbeg + mk + gr * 8;
            *(short8_t*)&Ar[row][gr * 8] = *(const short8_t*)(AxT_r + o);
            *(short8_t*)&Ai[row][gr * 8] = *(const short8_t*)(AxT_i + o);
        }
        #pragma unroll
        for (int it = 0; it < 2; ++it) {
            int e = tid + it * 256;
            int row = e >> 3, gr = e & 7;
            size_t o = (size_t)(y0 + row) * MSTR + kbeg + mk + gr * 8;
            short8_t yr = *(const short8_t*)(AyT_r + o);
            short8_t yi = *(const short8_t*)(AyT_i + o);
            short8_t br, bi2;
            #pragma unroll
            for (int j = 0; j < 8; ++j) {
                float2 k = kspl[mk + gr * 8 + j];
                float cr = bf2f((unsigned short)yr[j]);
                float ci = bf2f((unsigned short)yi[j]);
                br[j]  = (short)f2bf(k.x * cr - k.y * ci);
                bi2[j] = (short)f2bf(k.x * ci + k.y * cr);
            }
            *(short8_t*)&Br[row][gr * 8] = br;
            *(short8_t*)&Bi[row][gr * 8] = bi2;
        }
        __syncthreads();

        #pragma unroll
        for (int ks = 0; ks < 2; ++ks) {
            short8_t a_r[2], a_i[2], a_n[2], b_r[2], b_i[2];
            #pragma unroll
            for (int ix = 0; ix < 2; ++ix) {
                int rr = wx * 32 + ix * 16 + ar;
                a_r[ix] = *(const short8_t*)&Ar[rr][ks * 32 + kb * 8];
                a_i[ix] = *(const short8_t*)&Ai[rr][ks * 32 + kb * 8];
                a_n[ix] = neg8(a_i[ix]);
            }
            #pragma unroll
            for (int jy = 0; jy < 2; ++jy) {
                int cc = wyy * 32 + jy * 16 + ar;
                b_r[jy] = *(const short8_t*)&Br[cc][ks * 32 + kb * 8];
                b_i[jy] = *(const short8_t*)&Bi[cc][ks * 32 + kb * 8];
            }
            #pragma unroll
            for (int ix = 0; ix < 2; ++ix)
                #pragma unroll
                for (int jy = 0; jy < 2; ++jy) {
                    accR[ix][jy] = __builtin_amdgcn_mfma_f32_16x16x32_bf16(a_r[ix], b_r[jy], accR[ix][jy], 0, 0, 0);
                    accR[ix][jy] = __builtin_amdgcn_mfma_f32_16x16x32_bf16(a_n[ix], b_i[jy], accR[ix][jy], 0, 0, 0);
                    accI[ix][jy] = __builtin_amdgcn_mfma_f32_16x16x32_bf16(a_r[ix], b_i[jy], accI[ix][jy], 0, 0, 0);
                    accI[ix][jy] = __builtin_amdgcn_mfma_f32_16x16x32_bf16(a_i[ix], b_r[jy], accI[ix][jy], 0, 0, 0);
                }
        }
        __syncthreads();
    }

    #pragma unroll
    for (int ix = 0; ix < 2; ++ix)
        #pragma unroll
        for (int jy = 0; jy < 2; ++jy)
            #pragma unroll
            for (int q = 0; q < 4; ++q) {
                int x = x0 + wx * 32 + ix * 16 + kb * 4 + q;
                int y = y0 + wyy * 32 + jy * 16 + ar;
                size_t o = (((size_t)sk * BCC + bc) * NN + x) * NN + y;
                float vr = accR[ix][jy][q], vi = accI[ix][jy][q];
                if (FP32P) {
                    ((float2*)partial2)[o] = make_float2(vr, vi);
                } else {
                    ((unsigned*)partial2)[o] =
                        (unsigned)f2bf(vr) | ((unsigned)f2bf(vi) << 16);
                }
            }
}

// ============ reduce_out ============
template<int FP32P>
__global__ void reduce_out(const void* __restrict__ partial2,
                           float2* __restrict__ out)
{
    size_t total = (size_t)BCC * NN * NN;
    size_t idx = (size_t)blockIdx.x * 256 + threadIdx.x;
    if (idx >= total) return;
    float2 r = make_float2(0.f, 0.f);
    #pragma unroll
    for (int s = 0; s < SKADJ; ++s) {
        if (FP32P) {
            float2 v = ((const float2*)partial2)[s * total + idx];
            r.x += v.x; r.y += v.y;
        } else {
            unsigned u = ((const unsigned*)partial2)[s * total + idx];
            r.x += bf2f((unsigned short)(u & 0xffff));
            r.y += bf2f((unsigned short)(u >> 16));
        }
    }
    out[idx] = r;
}

// ============ host ============
extern "C" void kernel_launch(void* const* d_in, const int* in_sizes, int n_in,
                              void* d_out, int out_size, void* d_ws, size_t ws_size,
                              hipStream_t stream)
{
    const float* inp  = (const float*)d_in[0];
    const float* traj = (const float*)d_in[1];

    char* ws = (char*)d_ws;
    const size_t PL = (size_t)NN * MSTR * 2;           // 3,932,160 B per bf16 plane
    unsigned short* AxT_r = (unsigned short*)(ws);
    unsigned short* AxT_i = (unsigned short*)(ws + PL);
    unsigned short* AyT_r = (unsigned short*)(ws + 2 * PL);
    unsigned short* AyT_i = (unsigned short*)(ws + 3 * PL);
    float2* ksp = (float2*)(ws + 4 * PL);
    const size_t KSPB = (size_t)BCC * MSTR * 8;        // 393,216
    const size_t BASE = 4 * PL + KSPB;                 // 16,121,856
    char* rb = ws + BASE;
    // fwd phase (dead after reduce_ksp; aliases U region):
    unsigned short* Ax_r = (unsigned short*)(rb);
    unsigned short* Ax_i = (unsigned short*)(rb + PL);
    const size_t ITP = (size_t)BCC * NN * NN * 2;      // 1,638,400 per plane
    unsigned short* iT_r = (unsigned short*)(rb + 2 * PL);
    unsigned short* iT_i = (unsigned short*)(rb + 2 * PL + ITP);
    float2* partial1 = (float2*)(rb + 2 * PL + 2 * ITP);
    // adj phase:
    const size_t UPL = (size_t)BCC * NN * MSTR * 2;    // 31,457,280 per U plane
    unsigned short* U_r = (unsigned short*)(rb);
    unsigned short* U_i = (unsigned short*)(rb + UPL);
    const size_t ADJ_F32 = (size_t)SKADJ * BCC * NN * NN * 8;   // 52,428,800
    const size_t ADJ_B16 = ADJ_F32 / 2;                         // 26,214,400

    gen_A<<<dim3(96, 5), 256, 0, stream>>>(traj, Ax_r, Ax_i, AxT_r, AxT_i, AyT_r, AyT_i);
    conv_img<<<dim3(5, 5, BCC), 256, 0, stream>>>(inp, iT_r, iT_i);
    fwd_gemm<<<dim3(1880), 256, 0, stream>>>(iT_r, iT_i, Ax_r, Ax_i, AyT_r, AyT_i, partial1);
    reduce_ksp<<<dim3(24, BCC), 256, 0, stream>>>(partial1, ksp);

    size_t total = (size_t)BCC * NN * NN;
    int rblocks = (int)((total + 255) / 256);

    if (ws_size >= BASE + 2 * UPL + ADJ_F32) {
        void* partial2 = (void*)(rb + 2 * UPL);
        gen_U<<<dim3(3, NN, BCC), 256, 0, stream>>>(AyT_r, AyT_i, ksp, U_r, U_i);
        adj_gemm_pre<1><<<dim3(NADJB), 256, 0, stream>>>(AxT_r, AxT_i, U_r, U_i, partial2);
        reduce_out<1><<<rblocks, 256, 0, stream>>>(partial2, (float2*)d_out);
    } else if (ws_size >= BASE + 2 * UPL + ADJ_B16) {
        void* partial2 = (void*)(rb + 2 * UPL);
        gen_U<<<dim3(3, NN, BCC), 256, 0, stream>>>(AyT_r, AyT_i, ksp, U_r, U_i);
        adj_gemm_pre<0><<<dim3(NADJB), 256, 0, stream>>>(AxT_r, AxT_i, U_r, U_i, partial2);
        reduce_out<0><<<rblocks, 256, 0, stream>>>(partial2, (float2*)d_out);
    } else if (ws_size >= BASE + ADJ_F32) {
        void* partial2 = (void*)rb;
        adj_gemm_fb<1><<<dim3(NADJB), 256, 0, stream>>>(AxT_r, AxT_i, AyT_r, AyT_i, ksp, partial2);
        reduce_out<1><<<rblocks, 256, 0, stream>>>(partial2, (float2*)d_out);
    } else {
        void* partial2 = (void*)rb;
        adj_gemm_fb<0><<<dim3(NADJB), 256, 0, stream>>>(AxT_r, AxT_i, AyT_r, AyT_i, ksp, partial2);
        reduce_out<0><<<rblocks, 256, 0, stream>>>(partial2, (float2*)d_out);
    }
}